// Round 7
// baseline (305.996 us; speedup 1.0000x reference)
//
#include <hip/hip_runtime.h>

#define BB 16
#define NN 1000
#define DD 256
#define LL 3
#define MAXNZ 256
#define MROWS (BB * NN)
#define SPLIT_SCALE 2048.0f
#define INV_SPLIT 4.8828125e-4f

typedef _Float16 f16x8 __attribute__((ext_vector_type(8)));
typedef _Float16 f16x2 __attribute__((ext_vector_type(2)));
typedef float f32x4 __attribute__((ext_vector_type(4)));

union H8 { f16x8 v; f16x2 p[4]; _Float16 h[8]; int4 i4; };

#if defined(__has_builtin)
#if __has_builtin(__builtin_amdgcn_fdot2)
#define HAS_FDOT2 1
#endif
#endif

__device__ __forceinline__ float dot2f(f16x2 a, f16x2 b, float c) {
#ifdef HAS_FDOT2
    return __builtin_amdgcn_fdot2(a, b, c, false);
#else
    return fmaf((float)a[0], (float)b[0], fmaf((float)a[1], (float)b[1], c));
#endif
}

// ---------------------------------------------------------------------------
// Kernel 0a: split+transpose the 10 weight matrices -> wt[mat][n][k] hi/lo.
// ---------------------------------------------------------------------------
__global__ __launch_bounds__(256) void convert_w(
    const float* __restrict__ W_list, const float* __restrict__ dense_W,
    const float* __restrict__ final_W,
    _Float16* __restrict__ wt_hi, _Float16* __restrict__ wt_lo)
{
    __shared__ float T[64][68];
    int blk = blockIdx.x;          // 10 mats * 16 tiles
    int mat = blk >> 4;
    int tile = blk & 15;
    int tk = (tile >> 2) * 64, tn = (tile & 3) * 64;
    const float* src = (mat < 3) ? (W_list + (size_t)mat * 65536)
                     : (mat < 9) ? (dense_W + (size_t)(mat - 3) * 65536)
                                 : final_W;
    int t = threadIdx.x;
    {
        int k = t >> 2, nc = (t & 3) * 16;
        const float* sp = src + (size_t)(tk + k) * 256 + tn + nc;
        *(float4*)&T[k][nc + 0]  = *(const float4*)(sp + 0);
        *(float4*)&T[k][nc + 4]  = *(const float4*)(sp + 4);
        *(float4*)&T[k][nc + 8]  = *(const float4*)(sp + 8);
        *(float4*)&T[k][nc + 12] = *(const float4*)(sp + 12);
    }
    __syncthreads();
    int n = t >> 2, kc = (t & 3) * 16;
    H8 hh0, hh1, ll0, ll1;
    #pragma unroll
    for (int i = 0; i < 16; ++i) {
        float x = T[kc + i][n];
        _Float16 hi = (_Float16)x;
        _Float16 lo = (_Float16)((x - (float)hi) * SPLIT_SCALE);
        if (i < 8) { hh0.h[i] = hi; ll0.h[i] = lo; }
        else       { hh1.h[i - 8] = hi; ll1.h[i - 8] = lo; }
    }
    size_t o = (size_t)mat * 65536 + (size_t)(tn + n) * 256 + tk + kc;
    *(int4*)(wt_hi + o)     = hh0.i4;
    *(int4*)(wt_hi + o + 8) = hh1.i4;
    *(int4*)(wt_lo + o)     = ll0.i4;
    *(int4*)(wt_lo + o + 8) = ll1.i4;
}

// ---------------------------------------------------------------------------
// Kernel 0b: split x_in fp32 -> hi/lo fp16 planes.
// ---------------------------------------------------------------------------
__global__ __launch_bounds__(256) void convert_x(
    const float* __restrict__ in, _Float16* __restrict__ hi,
    _Float16* __restrict__ lo)
{
    size_t gid = (size_t)blockIdx.x * 256 + threadIdx.x;
    const float* p = in + gid * 8;
    float4 a = *(const float4*)p;
    float4 b = *(const float4*)(p + 4);
    float xs[8] = {a.x, a.y, a.z, a.w, b.x, b.y, b.z, b.w};
    H8 hh, ll;
    #pragma unroll
    for (int i = 0; i < 8; ++i) {
        _Float16 h = (_Float16)xs[i];
        hh.h[i] = h;
        ll.h[i] = (_Float16)((xs[i] - (float)h) * SPLIT_SCALE);
    }
    *(int4*)(hi + gid * 8) = hh.i4;
    *(int4*)(lo + gid * 8) = ll.i4;
}

// ---------------------------------------------------------------------------
// Kernel 1: build sparse structure of A = prot_contacts + eye.
// ---------------------------------------------------------------------------
__global__ __launch_bounds__(256) void build_sparse(
    const float* __restrict__ contacts,
    int* __restrict__ idx, int* __restrict__ cnt, float* __restrict__ adiag)
{
    int wave = (int)((blockIdx.x * blockDim.x + threadIdx.x) >> 6);
    int lane = threadIdx.x & 63;
    if (wave >= MROWS) return;
    int b = wave / NN;
    int i = wave - b * NN;
    const float* row = contacts + (size_t)b * NN * NN + (size_t)i * NN;
    int* out = idx + (size_t)wave * MAXNZ;
    int count = 0;
    for (int j0 = 0; j0 < NN; j0 += 64) {
        int j = j0 + lane;
        float v = (j < NN) ? row[j] : 0.0f;
        bool p = (v != 0.0f) && (j != i);
        unsigned long long bal = __ballot(p);
        if (p) {
            int pre = __popcll(bal & ((1ull << lane) - 1ull));
            out[count + pre] = j;
        }
        count += __popcll(bal);
    }
    if (lane == 0) {
        cnt[wave] = count;
        adiag[wave] = row[i] + 1.0f;
    }
}

// ---------------------------------------------------------------------------
// Kernel 2: sparse attention aggregate v5.
// TWO waves per row (neighbor-parity split) -> 8 neighbors in flight per row.
// 16-lane group s holds dims [8s..8s+7] u [128+8s..128+8s+7].
// Cross-wave combine via 2KB LDS. XCD-local row chunks.
// ---------------------------------------------------------------------------
__global__ __launch_bounds__(256) void sparse_agg(
    const _Float16* __restrict__ yhi,
    const _Float16* __restrict__ xhi, const _Float16* __restrict__ xlo,
    const int* __restrict__ idx, const int* __restrict__ cnt,
    const float* __restrict__ adiag,
    _Float16* __restrict__ ohi, _Float16* __restrict__ olo)
{
    __shared__ float red[2][257];
    int bid = blockIdx.x;            // 8000 blocks
    int xcd = bid & 7;
    int chunk = bid >> 3;            // 0..999
    int w = (int)(threadIdx.x >> 6); // 0..3
    int rib = w >> 1;                // row-in-block
    int h = w & 1;                   // neighbor parity handled by this wave
    int row = xcd * 2000 + chunk * 2 + rib;
    row = __builtin_amdgcn_readfirstlane(row);
    int lane = threadIdx.x & 63;
    int g = lane >> 4, s = lane & 15;
    int b = row / NN;

    const _Float16* yp = yhi + (size_t)row * DD + s * 8;
    H8 yh0, yh1;
    yh0.i4 = *(const int4*)yp;
    yh1.i4 = *(const int4*)(yp + 128);
    const _Float16* xb = xhi + (size_t)b * NN * DD;

    float denom = 0.0f;
    float acc[16];
    #pragma unroll
    for (int u = 0; u < 16; ++u) acc[u] = 0.0f;

    // wave h==0 handles the diagonal term (recombined hi+lo own row)
    if (h == 0) {
        const _Float16* xph = xhi + (size_t)row * DD + s * 8;
        const _Float16* xpl = xlo + (size_t)row * DD + s * 8;
        H8 xih0, xih1, xil0, xil1;
        xih0.i4 = *(const int4*)xph;   xih1.i4 = *(const int4*)(xph + 128);
        xil0.i4 = *(const int4*)xpl;   xil1.i4 = *(const int4*)(xpl + 128);
        float xi[16];
        #pragma unroll
        for (int u = 0; u < 8; ++u) {
            xi[u]     = fmaf((float)xil0.h[u], INV_SPLIT, (float)xih0.h[u]);
            xi[8 + u] = fmaf((float)xil1.h[u], INV_SPLIT, (float)xih1.h[u]);
        }
        float p = 0.0f;
        #pragma unroll
        for (int u = 0; u < 8; ++u) {
            p = fmaf((float)yh0.h[u], xi[u], p);
            p = fmaf((float)yh1.h[u], xi[8 + u], p);
        }
        p += __shfl_xor(p, 1); p += __shfl_xor(p, 2);
        p += __shfl_xor(p, 4); p += __shfl_xor(p, 8);
        float wd = (g == 0) ? (__expf(p) + 1e-5f) * adiag[row] : 0.0f;
        denom = wd;
        #pragma unroll
        for (int u = 0; u < 16; ++u)
            acc[u] = wd * ((u < 8) ? xi[u] : xi[u]);
        #pragma unroll
        for (int u = 0; u < 16; ++u) acc[u] = wd * xi[u];
    }

    const int c = cnt[row];
    const int* ip = idx + (size_t)row * MAXNZ;
    const int pbase = 2 * g + h;          // this group's first neighbor position
    const int iters = (c + 7) >> 3;

    // pipeline prologue
    int j0 = (pbase < c) ? ip[pbase] : 0;
    int j1 = (8 + pbase < c) ? ip[8 + pbase] : 0;
    bool vok = pbase < c;
    H8 v0, v1;
    {
        const _Float16* xp = xb + (size_t)j0 * DD + s * 8;
        v0.i4 = *(const int4*)xp;
        v1.i4 = *(const int4*)(xp + 128);
    }

    for (int t = 0; t < iters; ++t) {
        int k2 = (t + 2) * 8 + pbase;
        int j2 = (k2 < c) ? ip[k2] : 0;
        H8 n0, n1;
        const _Float16* np = xb + (size_t)j1 * DD + s * 8;
        n0.i4 = *(const int4*)np;
        n1.i4 = *(const int4*)(np + 128);

        float q = 0.0f;
        #pragma unroll
        for (int i = 0; i < 4; ++i) q = dot2f(yh0.p[i], v0.p[i], q);
        #pragma unroll
        for (int i = 0; i < 4; ++i) q = dot2f(yh1.p[i], v1.p[i], q);
        q += __shfl_xor(q, 1); q += __shfl_xor(q, 2);
        q += __shfl_xor(q, 4); q += __shfl_xor(q, 8);
        float wq = vok ? __expf(q) : 0.0f;
        denom += wq;
        #pragma unroll
        for (int u = 0; u < 8; ++u) {
            acc[u]     = fmaf(wq, (float)v0.h[u], acc[u]);
            acc[8 + u] = fmaf(wq, (float)v1.h[u], acc[8 + u]);
        }

        v0 = n0; v1 = n1;
        j1 = j2;
        vok = (t + 1) * 8 + pbase < c;
    }

    // cross-group reduction within wave (all groups end with full sums)
#define XG(x) x += __shfl_xor(x, 16); x += __shfl_xor(x, 32);
    XG(denom);
    #pragma unroll
    for (int u = 0; u < 16; ++u) { XG(acc[u]) }
#undef XG

    // cross-wave combine: odd wave publishes, even wave consumes
    if (h == 1 && g == 0) {
        #pragma unroll
        for (int u = 0; u < 8; ++u) {
            red[rib][s * 8 + u]       = acc[u];
            red[rib][128 + s * 8 + u] = acc[8 + u];
        }
        if (s == 0) red[rib][256] = denom;
    }
    __syncthreads();
    if (h == 0) {
        #pragma unroll
        for (int u = 0; u < 8; ++u) {
            acc[u]     += red[rib][s * 8 + u];
            acc[8 + u] += red[rib][128 + s * 8 + u];
        }
        denom += red[rib][256];

        float inv = 1.0f / denom;
        // group g writes: g0 hi c0, g1 hi c1, g2 lo c0, g3 lo c1
        int half = (g & 1) * 8;
        H8 st;
        #pragma unroll
        for (int i = 0; i < 8; ++i) {
            float x = acc[half + i] * inv;
            _Float16 hh = (_Float16)x;
            st.h[i] = (g & 2) ? (_Float16)((x - (float)hh) * SPLIT_SCALE) : hh;
        }
        _Float16* dst = ((g & 2) ? olo : ohi) + (size_t)row * DD + (g & 1) * 128 + s * 8;
        *(int4*)dst = st.i4;
    }
}

// ---------------------------------------------------------------------------
// Kernel 3: split-fp16 MFMA GEMM v3 — software-pipelined reg prefetch.
// BM=64, BN=128, BK=64; 4 waves, wave tile 32x64 (2x4 of 16x16x32 MFMA).
// LDS XOR-swizzle byte ^= (row&7)<<4 on write and read.
// Loop: {barrier; write regs->LDS; barrier; prefetch G(kb+1); compute(kb)}.
// ---------------------------------------------------------------------------
__global__ __launch_bounds__(256, 2) void gemm16(
    const _Float16* __restrict__ Ahi, const _Float16* __restrict__ Alo,
    const _Float16* __restrict__ Bhi, const _Float16* __restrict__ Blo,
    const float* __restrict__ bias,
    const _Float16* __restrict__ Shi, const _Float16* __restrict__ Slo,
    _Float16* __restrict__ Chi, _Float16* __restrict__ Clo,
    float* __restrict__ Cf32, int relu)
{
    __shared__ __align__(16) char smem[49152];
    char* Ah = smem;             // [64 m][64 k] fp16 swizzled (8 KB)
    char* Al = smem + 8192;
    char* Bh = smem + 16384;     // [128 n][64 k] fp16 swizzled (16 KB)
    char* Bl = smem + 32768;

    int tid = threadIdx.x;
    int mBase = blockIdx.y * 64;
    int nBase = blockIdx.x * 128;

    int sm = tid >> 2, kc = (tid & 3) * 16;     // A staging: row, k-halves
    int sb = tid >> 1, kcb = (tid & 1) * 32;    // B staging
    const _Float16* gAh = Ahi + (size_t)(mBase + sm) * 256 + kc;
    const _Float16* gAl = Alo + (size_t)(mBase + sm) * 256 + kc;
    const _Float16* gBh = Bhi + (size_t)(nBase + sb) * 256 + kcb;
    const _Float16* gBl = Blo + (size_t)(nBase + sb) * 256 + kcb;
    int sbA = sm * 128 + kc * 2, swzA = (sm & 7) << 4;
    int sbB = sb * 128 + kcb * 2, swzB = (sb & 7) << 4;

    int l = tid & 63, wv = tid >> 6;
    int wm = (wv & 1) * 32, wn = (wv >> 1) * 64;
    int lr = l & 15, lkb = (l >> 4) * 16;

    f32x4 acc0[2][4] = {};
    f32x4 acc1[2][4] = {};

    int4 rA0, rA1, rA2, rA3;
    int4 rB0, rB1, rB2, rB3, rB4, rB5, rB6, rB7;
#define LOADG(kb) \
    rA0 = *(const int4*)(gAh + (kb));      rA1 = *(const int4*)(gAh + (kb) + 8);  \
    rA2 = *(const int4*)(gAl + (kb));      rA3 = *(const int4*)(gAl + (kb) + 8);  \
    rB0 = *(const int4*)(gBh + (kb));      rB1 = *(const int4*)(gBh + (kb) + 8);  \
    rB2 = *(const int4*)(gBh + (kb) + 16); rB3 = *(const int4*)(gBh + (kb) + 24); \
    rB4 = *(const int4*)(gBl + (kb));      rB5 = *(const int4*)(gBl + (kb) + 8);  \
    rB6 = *(const int4*)(gBl + (kb) + 16); rB7 = *(const int4*)(gBl + (kb) + 24);

    LOADG(0)

    #pragma unroll
    for (int kb = 0; kb < 256; kb += 64) {
        __syncthreads();
        *(int4*)(Ah + ((sbA +  0) ^ swzA)) = rA0;
        *(int4*)(Ah + ((sbA + 16) ^ swzA)) = rA1;
        *(int4*)(Al + ((sbA +  0) ^ swzA)) = rA2;
        *(int4*)(Al + ((sbA + 16) ^ swzA)) = rA3;
        *(int4*)(Bh + ((sbB +  0) ^ swzB)) = rB0;
        *(int4*)(Bh + ((sbB + 16) ^ swzB)) = rB1;
        *(int4*)(Bh + ((sbB + 32) ^ swzB)) = rB2;
        *(int4*)(Bh + ((sbB + 48) ^ swzB)) = rB3;
        *(int4*)(Bl + ((sbB +  0) ^ swzB)) = rB4;
        *(int4*)(Bl + ((sbB + 16) ^ swzB)) = rB5;
        *(int4*)(Bl + ((sbB + 32) ^ swzB)) = rB6;
        *(int4*)(Bl + ((sbB + 48) ^ swzB)) = rB7;
        __syncthreads();

        if (kb < 192) { LOADG(kb + 64) }   // prefetch next tile under compute

        #pragma unroll
        for (int kk = 0; kk < 2; ++kk) {
            int kby = kk * 64 + lkb;
            f16x8 fah[2], fal[2];
            #pragma unroll
            for (int mt = 0; mt < 2; ++mt) {
                int ml = wm + mt * 16 + lr;
                int off = (ml * 128 + kby) ^ ((ml & 7) << 4);
                fah[mt] = *(const f16x8*)(Ah + off);
                fal[mt] = *(const f16x8*)(Al + off);
            }
            f16x8 fbh[4], fbl[4];
            #pragma unroll
            for (int nt = 0; nt < 4; ++nt) {
                int nl = wn + nt * 16 + lr;
                int off = (nl * 128 + kby) ^ ((nl & 7) << 4);
                fbh[nt] = *(const f16x8*)(Bh + off);
                fbl[nt] = *(const f16x8*)(Bl + off);
            }
            #pragma unroll
            for (int mt = 0; mt < 2; ++mt)
                #pragma unroll
                for (int nt = 0; nt < 4; ++nt) {
                    acc0[mt][nt] = __builtin_amdgcn_mfma_f32_16x16x32_f16(
                        fah[mt], fbh[nt], acc0[mt][nt], 0, 0, 0);
                    acc1[mt][nt] = __builtin_amdgcn_mfma_f32_16x16x32_f16(
                        fah[mt], fbl[nt], acc1[mt][nt], 0, 0, 0);
                    acc1[mt][nt] = __builtin_amdgcn_mfma_f32_16x16x32_f16(
                        fal[mt], fbh[nt], acc1[mt][nt], 0, 0, 0);
                }
        }
    }
#undef LOADG

    #pragma unroll
    for (int mt = 0; mt < 2; ++mt) {
        #pragma unroll
        for (int nt = 0; nt < 4; ++nt) {
            int n = nBase + wn + nt * 16 + lr;
            float bv = bias ? bias[n] : 0.0f;
            #pragma unroll
            for (int q = 0; q < 4; ++q) {
                int m = mBase + wm + mt * 16 + (l >> 4) * 4 + q;
                size_t o = (size_t)m * 256 + n;
                float v = acc0[mt][nt][q] + acc1[mt][nt][q] * INV_SPLIT + bv;
                if (relu) v = fmaxf(v, 0.0f);
                if (Shi) v += (float)Shi[o] + (float)Slo[o] * INV_SPLIT;
                if (Cf32) {
                    Cf32[o] = v;
                } else {
                    _Float16 hh = (_Float16)v;
                    Chi[o] = hh;
                    Clo[o] = (_Float16)((v - (float)hh) * SPLIT_SCALE);
                }
            }
        }
    }
}

// ---------------------------------------------------------------------------
extern "C" void kernel_launch(void* const* d_in, const int* in_sizes, int n_in,
                              void* d_out, int out_size, void* d_ws, size_t ws_size,
                              hipStream_t stream)
{
    const float* x_in     = (const float*)d_in[0];
    const float* contacts = (const float*)d_in[1];
    const float* W_list   = (const float*)d_in[2];
    const float* dense_W  = (const float*)d_in[3];
    const float* dense_b  = (const float*)d_in[4];
    const float* final_W  = (const float*)d_in[5];
    const float* final_b  = (const float*)d_in[6];
    float* out = (float*)d_out;

    char* ws = (char*)d_ws;
    const size_t PL = (size_t)MROWS * DD;          // elements per plane
    _Float16* pl[8];
    for (int i = 0; i < 8; ++i) pl[i] = (_Float16*)ws + (size_t)i * PL;
    char* p8 = ws + 8 * PL * sizeof(_Float16);     // 65.5 MB
    int*   idx   = (int*)p8;
    int*   cnt   = (int*)(p8 + (size_t)MROWS * MAXNZ * sizeof(int));
    float* adiag = (float*)((char*)cnt + (size_t)MROWS * sizeof(int));
    _Float16* wt_hi = (_Float16*)((char*)adiag + (size_t)MROWS * sizeof(float));
    _Float16* wt_lo = wt_hi + (size_t)10 * 65536;

    convert_w<<<160, 256, 0, stream>>>(W_list, dense_W, final_W, wt_hi, wt_lo);
    convert_x<<<MROWS * DD / (256 * 8), 256, 0, stream>>>(x_in, pl[0], pl[1]);
    build_sparse<<<MROWS / 4, 256, 0, stream>>>(contacts, idx, cnt, adiag);

    dim3 gg(2, MROWS / 64);   // (2, 250)
    int cur = 0;
    for (int l = 0; l < LL; ++l) {
        int oth = 1 - cur;
        _Float16 *x0h = pl[2 * cur], *x0l = pl[2 * cur + 1];
        _Float16 *yh  = pl[2 * oth], *yl  = pl[2 * oth + 1];
        _Float16 *xah = pl[4], *xal = pl[5];
        _Float16 *xbh = pl[6], *xbl = pl[7];
        // y = x0 @ W_l
        gemm16<<<gg, 256, 0, stream>>>(x0h, x0l,
                                       wt_hi + (size_t)l * 65536,
                                       wt_lo + (size_t)l * 65536,
                                       nullptr, nullptr, nullptr,
                                       yh, yl, nullptr, 0);
        // sparse attention aggregate
        sparse_agg<<<MROWS / 2, 256, 0, stream>>>(yh, x0h, x0l, idx, cnt, adiag,
                                                  xah, xal);
        // dense 1 (relu)
        gemm16<<<gg, 256, 0, stream>>>(xah, xal,
                                       wt_hi + (size_t)(3 + l * 2) * 65536,
                                       wt_lo + (size_t)(3 + l * 2) * 65536,
                                       dense_b + (size_t)(l * 2 + 0) * 256,
                                       nullptr, nullptr,
                                       xbh, xbl, nullptr, 1);
        // dense 2 (relu) + skip(x0) -> next X0
        gemm16<<<gg, 256, 0, stream>>>(xbh, xbl,
                                       wt_hi + (size_t)(4 + l * 2) * 65536,
                                       wt_lo + (size_t)(4 + l * 2) * 65536,
                                       dense_b + (size_t)(l * 2 + 1) * 256,
                                       x0h, x0l,
                                       yh, yl, nullptr, 1);
        cur = oth;
    }
    // final projection -> fp32 d_out
    gemm16<<<gg, 256, 0, stream>>>(pl[2 * cur], pl[2 * cur + 1],
                                   wt_hi + (size_t)9 * 65536,
                                   wt_lo + (size_t)9 * 65536,
                                   final_b, nullptr, nullptr,
                                   nullptr, nullptr, out, 0);
}